// Round 3
// baseline (357.510 us; speedup 1.0000x reference)
//
#include <hip/hip_runtime.h>
#include <hip/hip_bf16.h>

#define DIM  256
#define NSEQ 8192
#define BATCH 8
#define WIN  512

typedef __attribute__((ext_vector_type(8))) short short8;   // bf16x8 MFMA frag (4 VGPRs)
typedef __attribute__((ext_vector_type(4))) float floatx4;  // MFMA acc

union PFU { int i[4]; short8 v; };

__device__ __forceinline__ int packbf(float a, float b) {
    __hip_bfloat162 h;
    h.x = __float2bfloat16(a);
    h.y = __float2bfloat16(b);
    int r;
    __builtin_memcpy(&r, &h, 4);
    return r;
}

__device__ __forceinline__ void gld_lds16(void* lds_dst, const void* g_src) {
    __builtin_amdgcn_global_load_lds(
        (const __attribute__((address_space(1))) void*)g_src,
        (__attribute__((address_space(3))) void*)lds_dst,
        16, 0, 0);
}

// ---------------------------------------------------------------------------
// Kernel 1: x (B, D, N) f32  ->  xT (B, N, D) bf16
// R8: write half vectorized (ushort4 stores, 4x fewer store instrs).
// ---------------------------------------------------------------------------
__global__ __launch_bounds__(256) void k_transpose(const float* __restrict__ x,
                                                   __hip_bfloat16* __restrict__ xT) {
    __shared__ float tile[64][65];
    const int b  = blockIdx.z;
    const int n0 = blockIdx.x * 64;
    const int d0 = blockIdx.y * 64;
    const int t  = threadIdx.x;
    const int ln = t & 63, grp = t >> 6;

    const float* xb = x + (size_t)b * DIM * NSEQ;
#pragma unroll
    for (int i = 0; i < 16; ++i) {
        int d = grp * 16 + i;
        tile[d][ln] = xb[(size_t)(d0 + d) * NSEQ + n0 + ln];
    }
    __syncthreads();
    __hip_bfloat16* xTb = xT + (size_t)b * NSEQ * DIM;
    const int a2 = t & 15, nr = t >> 4;   // a2: d-quad, nr: row-in-iter
#pragma unroll
    for (int i = 0; i < 4; ++i) {
        const int n = i * 16 + nr;
        union { __hip_bfloat16 h[4]; ushort4 u; } pk;
#pragma unroll
        for (int k = 0; k < 4; ++k)
            pk.h[k] = __float2bfloat16(tile[a2 * 4 + k][n]);
        *(ushort4*)(xTb + (size_t)(n0 + n) * DIM + d0 + a2 * 4) = pk.u;
    }
}

// ---------------------------------------------------------------------------
// Kernel 2: Wq,Wk,Wv f32 -> packed bf16 buffer wb[3][256*256]
// ---------------------------------------------------------------------------
__global__ __launch_bounds__(256) void k_wcast(const float* __restrict__ w0,
                                               const float* __restrict__ w1,
                                               const float* __restrict__ w2,
                                               __hip_bfloat16* __restrict__ wb) {
    int i = (blockIdx.x * 256 + threadIdx.x) * 4;
    const float* s = (i < 65536) ? (w0 + i) : ((i < 131072) ? (w1 + i - 65536) : (w2 + i - 131072));
    float4 v = *(const float4*)s;
    union { __hip_bfloat16 h[4]; ushort4 u; } cv;
    cv.h[0] = __float2bfloat16(v.x);
    cv.h[1] = __float2bfloat16(v.y);
    cv.h[2] = __float2bfloat16(v.z);
    cv.h[3] = __float2bfloat16(v.w);
    *(ushort4*)(wb + i) = cv.u;
}

// ---------------------------------------------------------------------------
// Kernel 3 (R8 rewrite): fused 3-mode projection, single barrier.
// Old structure: 3072 blocks x 16 barrier-pairs, A re-read ~6x (192 MB),
// 16 MFMA between barriers -> ~4x off roofline. New structure:
//  - block = 256 thr / 4 waves, m-tile = 64 rows, FULL K=256 of A staged
//    once into LDS (32 KB, chunk-major [ks][64][32]: row stride 64 B =
//    proven conflict-free m97 read pattern; gld_lds per-lane global src).
//  - W fragments read straight from global (L2-resident, 384 KB total);
//    no B staging, no barriers after the A stage. Wave owns 64 cols.
//  - per mode: 8 ks x {4 W-loads, 4 ds_reads, 16 MFMA}; modes sequential,
//    acc reused. A read from HBM exactly once (32 MB vs ~192 MB).
//  - v-mode: SWAP MFMA operand order (wf as A, af as B). A/B frags have
//    identical per-lane layout, so this transposes the C tile and the
//    vto[d][n] store keeps the 16-lane 32 B-segment coalescing.
// ---------------------------------------------------------------------------
__global__ __launch_bounds__(256, 3) void k_proj(const __hip_bfloat16* __restrict__ xT,
                                                 const __hip_bfloat16* __restrict__ wb,
                                                 const float* __restrict__ bq,
                                                 const float* __restrict__ bk,
                                                 const float* __restrict__ bv,
                                                 __hip_bfloat16* __restrict__ qo,
                                                 __hip_bfloat16* __restrict__ ko,
                                                 __hip_bfloat16* __restrict__ vto) {
    __shared__ __align__(16) char As[32768];   // [ks 8][row 64][64 B]
    const int b   = blockIdx.y;
    const int m0  = blockIdx.x * 64;
    const int tid = threadIdx.x;
    const int wv  = tid >> 6;
    const int l   = tid & 63;
    const int lm  = l & 15;
    const int qd  = l >> 4;
    const int wn  = wv * 64;   // this wave's 64-col slice

    const char* Ap = (const char*)(xT + ((size_t)b * NSEQ + m0) * DIM);
    // ---- stage A-tile 64 rows x 256 K (32 KB), chunk-major, once ----
#pragma unroll
    for (int ii = 0; ii < 8; ++ii) {
        const int ks = wv * 2 + (ii >> 2);
        const int r0 = (ii & 3) * 16;
        gld_lds16(As + ks * 4096 + r0 * 64,
                  Ap + (size_t)(r0 + (l >> 2)) * 512 + ks * 64 + (l & 3) * 16);
    }
    __syncthreads();   // compiler drains vmcnt before s_barrier

#pragma unroll
    for (int mode = 0; mode < 3; ++mode) {
        const __hip_bfloat16* wp = wb + mode * 65536;
        floatx4 acc[4][4];
#pragma unroll
        for (int i = 0; i < 4; ++i)
#pragma unroll
            for (int j = 0; j < 4; ++j) acc[i][j] = (floatx4){0.f, 0.f, 0.f, 0.f};

#pragma unroll
        for (int ks = 0; ks < 8; ++ks) {
            short8 wf[4], af[4];
#pragma unroll
            for (int j = 0; j < 4; ++j)
                wf[j] = *(const short8*)(wp + (size_t)(wn + j * 16 + lm) * DIM + ks * 32 + qd * 8);
#pragma unroll
            for (int j = 0; j < 4; ++j)
                af[j] = *(const short8*)(As + ks * 4096 + (j * 16 + lm) * 64 + qd * 16);
            if (mode < 2) {
#pragma unroll
                for (int mt = 0; mt < 4; ++mt)
#pragma unroll
                    for (int nt = 0; nt < 4; ++nt)
                        acc[mt][nt] = __builtin_amdgcn_mfma_f32_16x16x32_bf16(af[mt], wf[nt], acc[mt][nt], 0, 0, 0);
            } else {
#pragma unroll
                for (int jw = 0; jw < 4; ++jw)
#pragma unroll
                    for (int ja = 0; ja < 4; ++ja)
                        acc[jw][ja] = __builtin_amdgcn_mfma_f32_16x16x32_bf16(wf[jw], af[ja], acc[jw][ja], 0, 0, 0);
            }
        }

        if (mode < 2) {
            const float* bias = mode ? bk : bq;
            __hip_bfloat16* op = (mode ? ko : qo) + (size_t)b * NSEQ * DIM;
            float bc[4];
#pragma unroll
            for (int nt = 0; nt < 4; ++nt) bc[nt] = bias[wn + nt * 16 + lm];
#pragma unroll
            for (int mt = 0; mt < 4; ++mt)
#pragma unroll
                for (int nt = 0; nt < 4; ++nt)
#pragma unroll
                    for (int r = 0; r < 4; ++r)
                        op[(size_t)(m0 + mt * 16 + qd * 4 + r) * DIM + wn + nt * 16 + lm] =
                            __float2bfloat16(acc[mt][nt][r] + bc[nt]);
        } else {
            __hip_bfloat16* op = vto + (size_t)b * DIM * NSEQ;
#pragma unroll
            for (int jw = 0; jw < 4; ++jw)
#pragma unroll
                for (int r = 0; r < 4; ++r) {
                    const int d = wn + jw * 16 + qd * 4 + r;
                    const float bb = bv[d];
#pragma unroll
                    for (int ja = 0; ja < 4; ++ja)
                        op[(size_t)d * NSEQ + m0 + ja * 16 + lm] =
                            __float2bfloat16(acc[jw][ja][r] + bb);
                }
        }
    }
}

// ---------------------------------------------------------------------------
// Kernel 4: sliding-window flash attention (R7: T5 setprio + T13 defer-max).
// Unchanged this round.
// ---------------------------------------------------------------------------
__global__ __launch_bounds__(512, 2) void k_attn(const __hip_bfloat16* __restrict__ qm,
                                                 const __hip_bfloat16* __restrict__ km,
                                                 const __hip_bfloat16* __restrict__ vtm,
                                                 const float* __restrict__ x,
                                                 float* __restrict__ out) {
    __shared__ __align__(16) char kbuf[2][16384];
    __shared__ __align__(16) char vbuf[2][16384];

    const int w  = blockIdx.x, b = blockIdx.y, qt = blockIdx.z;
    const int tid = threadIdx.x;
    const int wv = tid >> 6;
    const int l  = tid & 63;
    const int m  = l & 15;   // q-row (and fragment row) within 16
    const int qd = l >> 4;   // quad

    const int qbw   = qt * 256 + wv * 32;  // wave q-base within window [0,512)
    const int koff0 = w * WIN - WIN;       // global row of key_local 0

    // ---- Q fragments for both q-tiles (private, once) ----
    short8 qf[2][8];
#pragma unroll
    for (int u = 0; u < 2; ++u) {
        const __hip_bfloat16* qrow =
            qm + ((size_t)b * NSEQ + (size_t)(w * WIN + qbw + u * 16 + m)) * DIM;
#pragma unroll
        for (int s = 0; s < 8; ++s)
            qf[u][s] = *(const short8*)(qrow + s * 32 + qd * 8);
    }

    const char* kbase = (const char*)(km + (size_t)b * NSEQ * DIM);
    const char* vbase = (const char*)(vtm + (size_t)b * DIM * NSEQ);

    const int c0  = (w == 0) ? 16 : 0;               // skip nonexistent prev window
    const int c1w = (512 + qbw + 63) >> 5;           // per-wave exclusive chunk end
    const int c1b = (799 + qt * 256) >> 5;           // block-level end (top wave)

    // ---- staging role ----
    const bool   isK     = wv < 4;
    const size_t gstride = isK ? (size_t)64 : (size_t)16 * NSEQ * 2;   // i-step
    const size_t adv     = isK ? (size_t)32 * 512 : (size_t)64;        // chunk-step
    const int    lbase   = (isK ? wv * 4 : (wv - 4) * 4) * 1024 + l * 16;
    const char* gp0;
    if (isK)
        gp0 = kbase + (size_t)(koff0 + c0 * 32 + (wv >> 1) * 16 + m) * 512 +
              (size_t)((wv & 1) * 16 + qd) * 16;
    else
        gp0 = vbase + (size_t)((wv - 4) * 64 + m) * (NSEQ * 2) +
              (size_t)(koff0 + c0 * 32) * 2 + (size_t)qd * 16;

    floatx4 o[2][16];
#pragma unroll
    for (int u = 0; u < 2; ++u)
#pragma unroll
        for (int t = 0; t < 16; ++t) o[u][t] = (floatx4){0.f, 0.f, 0.f, 0.f};
    float mi[2] = {-INFINITY, -INFINITY};
    float li[2] = {0.f, 0.f};
    const float sscale = 0.0625f * 1.4426950408889634f;  // D^-0.5 * log2(e)

    const int a0 = (((qd & 1) * 2) * 16 + m) * 4;  // bpermute byte addrs
    const int a1 = a0 + 64;
    const bool hi = (qd >> 1) != 0;

    // ---- prologue: stage chunk c0 into buf[0] ----
    int4 rg[4];
#pragma unroll
    for (int i = 0; i < 4; ++i)
        rg[i] = *(const int4*)(gp0 + (size_t)i * gstride);
    gp0 += adv;
    {
        char* d0 = (isK ? kbuf[0] : vbuf[0]) + lbase;
#pragma unroll
        for (int i = 0; i < 4; ++i)
            *(int4*)(d0 + i * 1024) = rg[i];
    }
    __syncthreads();  // buf[0] ready

    int pb = 0;
    for (int c = c0; c < c1b; ++c) {
        const bool more = (c + 1 < c1b);
        // ---- issue loads for chunk c+1 (in flight during compute) ----
        if (more) {
#pragma unroll
            for (int i = 0; i < 4; ++i)
                rg[i] = *(const int4*)(gp0 + (size_t)i * gstride);
            gp0 += adv;
        }
        // ---- compute chunk c from buf[pb] ----
        if (c < c1w) {
            const char* kbp = kbuf[pb];
            // S^T = K · Q^T, both q-tiles per kf read (2x reuse)
            floatx4 st[2][2];
#pragma unroll
            for (int u = 0; u < 2; ++u)
#pragma unroll
                for (int t = 0; t < 2; ++t) st[u][t] = (floatx4){0.f, 0.f, 0.f, 0.f};
            __builtin_amdgcn_s_setprio(1);   // T5: favor this wave while MFMAs issue
#pragma unroll
            for (int t = 0; t < 2; ++t)
#pragma unroll
                for (int s = 0; s < 8; ++s) {
                    short8 kf = *(const short8*)(kbp + ((t * 8 + s) * 64 + l) * 16);
                    st[0][t] = __builtin_amdgcn_mfma_f32_16x16x32_bf16(kf, qf[0][s], st[0][t], 0, 0, 0);
                    st[1][t] = __builtin_amdgcn_mfma_f32_16x16x32_bf16(kf, qf[1][s], st[1][t], 0, 0, 0);
                }
            __builtin_amdgcn_s_setprio(0);
            const int kl0 = c * 32;
            short8 pf[2];
#pragma unroll
            for (int u = 0; u < 2; ++u) {
                const int lim = 512 + qbw + u * 16 + m;
                const bool needmask = (kl0 + 31) > lim;
                float p[8];
#pragma unroll
                for (int t = 0; t < 2; ++t)
#pragma unroll
                    for (int r = 0; r < 4; ++r) {
                        float v = st[u][t][r] * sscale;
                        if (needmask) {
                            int key = kl0 + t * 16 + qd * 4 + r;
                            v = (key <= lim) ? v : -INFINITY;
                        }
                        p[t * 4 + r] = v;
                    }
                float mx = p[0];
#pragma unroll
                for (int i = 1; i < 8; ++i) mx = fmaxf(mx, p[i]);
                mx = fmaxf(mx, __shfl_xor(mx, 16, 64));
                mx = fmaxf(mx, __shfl_xor(mx, 32, 64));
                // T13 defer-max: if tile max grew <= 8 wave-wide, keep m_old.
                float mnew;
                if (__all(mx <= mi[u] + 8.0f)) mnew = mi[u];
                else                           mnew = fmaxf(mi[u], mx);
                const float alpha = exp2f(mi[u] - mnew);
                float ps = 0.f;
#pragma unroll
                for (int i = 0; i < 8; ++i) { p[i] = exp2f(p[i] - mnew); ps += p[i]; }
                ps += __shfl_xor(ps, 16, 64);
                ps += __shfl_xor(ps, 32, 64);
                li[u] = li[u] * alpha + ps;
                mi[u] = mnew;
                if (!__all(alpha == 1.0f)) {   // alpha==1 multiply is exact -> safe skip
#pragma unroll
                    for (int t = 0; t < 16; ++t) {
                        o[u][t][0] *= alpha; o[u][t][1] *= alpha;
                        o[u][t][2] *= alpha; o[u][t][3] *= alpha;
                    }
                }
                // pack P^T (bf16) + quad shuffle into B-fragment layout
                int pd0 = packbf(p[0], p[1]);
                int pd1 = packbf(p[2], p[3]);
                int pd2 = packbf(p[4], p[5]);
                int pd3 = packbf(p[6], p[7]);
                int x0 = __builtin_amdgcn_ds_bpermute(a0, pd0);
                int y0 = __builtin_amdgcn_ds_bpermute(a0, pd2);
                int x1 = __builtin_amdgcn_ds_bpermute(a0, pd1);
                int y1 = __builtin_amdgcn_ds_bpermute(a0, pd3);
                int x2 = __builtin_amdgcn_ds_bpermute(a1, pd0);
                int y2 = __builtin_amdgcn_ds_bpermute(a1, pd2);
                int x3 = __builtin_amdgcn_ds_bpermute(a1, pd1);
                int y3 = __builtin_amdgcn_ds_bpermute(a1, pd3);
                PFU pu;
                pu.i[0] = hi ? y0 : x0;
                pu.i[1] = hi ? y1 : x1;
                pu.i[2] = hi ? y2 : x2;
                pu.i[3] = hi ? y3 : x3;
                pf[u] = pu.v;
            }
            // O^T += V^T · P^T, both q-tiles per vf read (2x reuse)
            const char* vbp = vbuf[pb];
            __builtin_amdgcn_s_setprio(1);   // T5
#pragma unroll
            for (int t = 0; t < 16; ++t) {
                short8 vf = *(const short8*)(vbp + (t * 64 + l) * 16);
                o[0][t] = __builtin_amdgcn_mfma_f32_16x16x32_bf16(vf, pf[0], o[0][t], 0, 0, 0);
                o[1][t] = __builtin_amdgcn_mfma_f32_16x16x32_bf16(vf, pf[1], o[1][t], 0, 0, 0);
            }
            __builtin_amdgcn_s_setprio(0);
        }
        // ---- stage chunk c+1 (regs -> buf[pb^1]); rg dies here, same iter ----
        if (more) {
            char* dst = (isK ? kbuf[pb ^ 1] : vbuf[pb ^ 1]) + lbase;
#pragma unroll
            for (int i = 0; i < 4; ++i)
                *(int4*)(dst + i * 1024) = rg[i];
        }
        __syncthreads();
        pb ^= 1;
    }

    // ---- epilogue: O/l + residual, write out[b][d][n] (coalesced in n) ----
#pragma unroll
    for (int u = 0; u < 2; ++u) {
        const float inv = 1.f / li[u];
        const int ng = w * WIN + qbw + u * 16 + m;
        const float* xr  = x   + (size_t)b * DIM * NSEQ + ng;
        float*       orw = out + (size_t)b * DIM * NSEQ + ng;
#pragma unroll
        for (int t = 0; t < 16; ++t)
#pragma unroll
            for (int r = 0; r < 4; ++r) {
                int d = t * 16 + qd * 4 + r;
                orw[(size_t)d * NSEQ] = xr[(size_t)d * NSEQ] + o[u][t][r] * inv;
            }
    }
}

// ---------------------------------------------------------------------------
extern "C" void kernel_launch(void* const* d_in, const int* in_sizes, int n_in,
                              void* d_out, int out_size, void* d_ws, size_t ws_size,
                              hipStream_t stream) {
    const float* x  = (const float*)d_in[0];
    const float* Wq = (const float*)d_in[1];
    const float* bq = (const float*)d_in[2];
    const float* Wk = (const float*)d_in[3];
    const float* bk = (const float*)d_in[4];
    const float* Wv = (const float*)d_in[5];
    const float* bv = (const float*)d_in[6];

    char* ws = (char*)d_ws;
    const size_t SZ = (size_t)BATCH * NSEQ * DIM * sizeof(__hip_bfloat16);  // 32 MB
    __hip_bfloat16* xT  = (__hip_bfloat16*)(ws);
    __hip_bfloat16* qb_ = (__hip_bfloat16*)(ws + SZ);
    __hip_bfloat16* kb_ = (__hip_bfloat16*)(ws + 2 * SZ);
    __hip_bfloat16* vt_ = (__hip_bfloat16*)(ws + 3 * SZ);
    __hip_bfloat16* wb_ = (__hip_bfloat16*)(ws + 4 * SZ);                   // 384 KB

    k_transpose<<<dim3(NSEQ / 64, DIM / 64, BATCH), 256, 0, stream>>>(x, xT);
    k_wcast<<<dim3(192), 256, 0, stream>>>(Wq, Wk, Wv, wb_);
    k_proj<<<dim3(NSEQ / 64, BATCH), 256, 0, stream>>>(xT, wb_, bq, bk, bv, qb_, kb_, vt_);
    k_attn<<<dim3(16, BATCH, 2), 512, 0, stream>>>(qb_, kb_, vt_, x, (float*)d_out);
}

// Round 4
// 347.616 us; speedup vs baseline: 1.0285x; 1.0285x over previous
//
#include <hip/hip_runtime.h>
#include <hip/hip_bf16.h>

#define DIM  256
#define NSEQ 8192
#define BATCH 8
#define WIN  512

typedef __attribute__((ext_vector_type(8))) short short8;   // bf16x8 MFMA frag (4 VGPRs)
typedef __attribute__((ext_vector_type(4))) float floatx4;  // MFMA acc

union PFU { int i[4]; short8 v; };

__device__ __forceinline__ int packbf(float a, float b) {
    __hip_bfloat162 h;
    h.x = __float2bfloat16(a);
    h.y = __float2bfloat16(b);
    int r;
    __builtin_memcpy(&r, &h, 4);
    return r;
}

// ---------------------------------------------------------------------------
// Kernel 1: Wq,Wk,Wv f32 -> packed bf16 buffer wb[3][256*256]
// ---------------------------------------------------------------------------
__global__ __launch_bounds__(256) void k_wcast(const float* __restrict__ w0,
                                               const float* __restrict__ w1,
                                               const float* __restrict__ w2,
                                               __hip_bfloat16* __restrict__ wb) {
    int i = (blockIdx.x * 256 + threadIdx.x) * 4;
    const float* s = (i < 65536) ? (w0 + i) : ((i < 131072) ? (w1 + i - 65536) : (w2 + i - 131072));
    float4 v = *(const float4*)s;
    union { __hip_bfloat16 h[4]; ushort4 u; } cv;
    cv.h[0] = __float2bfloat16(v.x);
    cv.h[1] = __float2bfloat16(v.y);
    cv.h[2] = __float2bfloat16(v.z);
    cv.h[3] = __float2bfloat16(v.w);
    *(ushort4*)(wb + i) = cv.u;
}

// ---------------------------------------------------------------------------
// Kernel 2 (R9): FUSED transpose + 3-mode projection. Kills the xT
// intermediate (67 MB HBM round-trip) and one kernel launch.
//
// Block = 256 thr / 4 waves, 64 n-rows x full K=256, grid (128, B).
// Phase A (4 slabs of 64 d): read x[b][d][n0:n0+64] f32 (float4, coalesced),
//   stage via padded f32 tile ftile[64][68] (write class (dr+nseg)&7 uniform;
//   transposed column reads stride-1), pack bf16 into As.
// As layout is SEG-MAJOR [ks 8][seg 4][row 64][8 d] (addr = ks*4096 +
//   seg*1024 + row*16 + (d&7)*2): b128 write class = l&7 (uniform,
//   conflict-free), b128 read class = lm&7 (uniform, conflict-free).
//   Same af fragment semantics as the verified R8 body.
// Phase B: identical to R8 proj (W frags from global/L2; v-mode via swapped
//   MFMA operands so vto[d][n] stores stay coalesced).
// ---------------------------------------------------------------------------
__global__ __launch_bounds__(256, 3) void k_prep(const float* __restrict__ x,
                                                 const __hip_bfloat16* __restrict__ wb,
                                                 const float* __restrict__ bq,
                                                 const float* __restrict__ bk,
                                                 const float* __restrict__ bv,
                                                 __hip_bfloat16* __restrict__ qo,
                                                 __hip_bfloat16* __restrict__ ko,
                                                 __hip_bfloat16* __restrict__ vto) {
    __shared__ float ftile[64][68];                 // 17.4 KB, padded (16B-aligned rows)
    __shared__ __align__(16) char As[32768];        // 32 KB bf16 A-tile, seg-major
    const int b   = blockIdx.y;
    const int n0  = blockIdx.x * 64;
    const int tid = threadIdx.x;
    const int wv  = tid >> 6;
    const int l   = tid & 63;
    const int lm  = l & 15;
    const int qd  = l >> 4;
    const int wn  = wv * 64;   // this wave's 64-col slice (Phase B)

    const float* xb = x + (size_t)b * DIM * NSEQ;

    // ---- Phase A: transpose+convert 256d x 64n of x into As ----
    const int dr = l >> 4, nseg = l & 15;
#pragma unroll
    for (int dsl = 0; dsl < 4; ++dsl) {
        const int d0 = dsl * 64;
        // step 1: wave wv loads d-rows [wv*16, wv*16+16) of this slab
#pragma unroll
        for (int i = 0; i < 4; ++i) {
            const int r = wv * 16 + i * 4 + dr;
            float4 v = *(const float4*)(xb + (size_t)(d0 + r) * NSEQ + n0 + nseg * 4);
            *(float4*)&ftile[r][nseg * 4] = v;
        }
        __syncthreads();
        // step 2: transposed read + bf16 pack -> As (conflict-free b128 writes)
#pragma unroll
        for (int p = 0; p < 2; ++p) {
            const int ks = dsl * 2 + p;
            int4 pk;
            int* pki = (int*)&pk;
#pragma unroll
            for (int jj = 0; jj < 4; ++jj)
                pki[jj] = packbf(ftile[p * 32 + wv * 8 + jj * 2][l],
                                 ftile[p * 32 + wv * 8 + jj * 2 + 1][l]);
            *(int4*)(As + ks * 4096 + wv * 1024 + l * 16) = pk;
        }
        __syncthreads();
    }

    // ---- Phase B: 3 projection GEMMs from As (R8 body) ----
#pragma unroll
    for (int mode = 0; mode < 3; ++mode) {
        const __hip_bfloat16* wp = wb + mode * 65536;
        floatx4 acc[4][4];
#pragma unroll
        for (int i = 0; i < 4; ++i)
#pragma unroll
            for (int j = 0; j < 4; ++j) acc[i][j] = (floatx4){0.f, 0.f, 0.f, 0.f};

#pragma unroll
        for (int ks = 0; ks < 8; ++ks) {
            short8 wf[4], af[4];
#pragma unroll
            for (int j = 0; j < 4; ++j)
                wf[j] = *(const short8*)(wp + (size_t)(wn + j * 16 + lm) * DIM + ks * 32 + qd * 8);
#pragma unroll
            for (int j = 0; j < 4; ++j)
                af[j] = *(const short8*)(As + ks * 4096 + qd * 1024 + (j * 16 + lm) * 16);
            if (mode < 2) {
#pragma unroll
                for (int mt = 0; mt < 4; ++mt)
#pragma unroll
                    for (int nt = 0; nt < 4; ++nt)
                        acc[mt][nt] = __builtin_amdgcn_mfma_f32_16x16x32_bf16(af[mt], wf[nt], acc[mt][nt], 0, 0, 0);
            } else {
#pragma unroll
                for (int jw = 0; jw < 4; ++jw)
#pragma unroll
                    for (int ja = 0; ja < 4; ++ja)
                        acc[jw][ja] = __builtin_amdgcn_mfma_f32_16x16x32_bf16(wf[jw], af[ja], acc[jw][ja], 0, 0, 0);
            }
        }

        if (mode < 2) {
            const float* bias = mode ? bk : bq;
            __hip_bfloat16* op = (mode ? ko : qo) + (size_t)b * NSEQ * DIM;
            float bc[4];
#pragma unroll
            for (int nt = 0; nt < 4; ++nt) bc[nt] = bias[wn + nt * 16 + lm];
#pragma unroll
            for (int mt = 0; mt < 4; ++mt)
#pragma unroll
                for (int nt = 0; nt < 4; ++nt)
#pragma unroll
                    for (int r = 0; r < 4; ++r)
                        op[(size_t)(n0 + mt * 16 + qd * 4 + r) * DIM + wn + nt * 16 + lm] =
                            __float2bfloat16(acc[mt][nt][r] + bc[nt]);
        } else {
            __hip_bfloat16* op = vto + (size_t)b * DIM * NSEQ;
#pragma unroll
            for (int jw = 0; jw < 4; ++jw)
#pragma unroll
                for (int r = 0; r < 4; ++r) {
                    const int d = wn + jw * 16 + qd * 4 + r;
                    const float bb = bv[d];
#pragma unroll
                    for (int ja = 0; ja < 4; ++ja)
                        op[(size_t)d * NSEQ + n0 + ja * 16 + lm] =
                            __float2bfloat16(acc[jw][ja][r] + bb);
                }
        }
    }
}

// ---------------------------------------------------------------------------
// Kernel 3: sliding-window flash attention (R7: T5 setprio + T13 defer-max).
// Unchanged this round.
// ---------------------------------------------------------------------------
__global__ __launch_bounds__(512, 2) void k_attn(const __hip_bfloat16* __restrict__ qm,
                                                 const __hip_bfloat16* __restrict__ km,
                                                 const __hip_bfloat16* __restrict__ vtm,
                                                 const float* __restrict__ x,
                                                 float* __restrict__ out) {
    __shared__ __align__(16) char kbuf[2][16384];
    __shared__ __align__(16) char vbuf[2][16384];

    const int w  = blockIdx.x, b = blockIdx.y, qt = blockIdx.z;
    const int tid = threadIdx.x;
    const int wv = tid >> 6;
    const int l  = tid & 63;
    const int m  = l & 15;   // q-row (and fragment row) within 16
    const int qd = l >> 4;   // quad

    const int qbw   = qt * 256 + wv * 32;  // wave q-base within window [0,512)
    const int koff0 = w * WIN - WIN;       // global row of key_local 0

    // ---- Q fragments for both q-tiles (private, once) ----
    short8 qf[2][8];
#pragma unroll
    for (int u = 0; u < 2; ++u) {
        const __hip_bfloat16* qrow =
            qm + ((size_t)b * NSEQ + (size_t)(w * WIN + qbw + u * 16 + m)) * DIM;
#pragma unroll
        for (int s = 0; s < 8; ++s)
            qf[u][s] = *(const short8*)(qrow + s * 32 + qd * 8);
    }

    const char* kbase = (const char*)(km + (size_t)b * NSEQ * DIM);
    const char* vbase = (const char*)(vtm + (size_t)b * DIM * NSEQ);

    const int c0  = (w == 0) ? 16 : 0;               // skip nonexistent prev window
    const int c1w = (512 + qbw + 63) >> 5;           // per-wave exclusive chunk end
    const int c1b = (799 + qt * 256) >> 5;           // block-level end (top wave)

    // ---- staging role ----
    const bool   isK     = wv < 4;
    const size_t gstride = isK ? (size_t)64 : (size_t)16 * NSEQ * 2;   // i-step
    const size_t adv     = isK ? (size_t)32 * 512 : (size_t)64;        // chunk-step
    const int    lbase   = (isK ? wv * 4 : (wv - 4) * 4) * 1024 + l * 16;
    const char* gp0;
    if (isK)
        gp0 = kbase + (size_t)(koff0 + c0 * 32 + (wv >> 1) * 16 + m) * 512 +
              (size_t)((wv & 1) * 16 + qd) * 16;
    else
        gp0 = vbase + (size_t)((wv - 4) * 64 + m) * (NSEQ * 2) +
              (size_t)(koff0 + c0 * 32) * 2 + (size_t)qd * 16;

    floatx4 o[2][16];
#pragma unroll
    for (int u = 0; u < 2; ++u)
#pragma unroll
        for (int t = 0; t < 16; ++t) o[u][t] = (floatx4){0.f, 0.f, 0.f, 0.f};
    float mi[2] = {-INFINITY, -INFINITY};
    float li[2] = {0.f, 0.f};
    const float sscale = 0.0625f * 1.4426950408889634f;  // D^-0.5 * log2(e)

    const int a0 = (((qd & 1) * 2) * 16 + m) * 4;  // bpermute byte addrs
    const int a1 = a0 + 64;
    const bool hi = (qd >> 1) != 0;

    // ---- prologue: stage chunk c0 into buf[0] ----
    int4 rg[4];
#pragma unroll
    for (int i = 0; i < 4; ++i)
        rg[i] = *(const int4*)(gp0 + (size_t)i * gstride);
    gp0 += adv;
    {
        char* d0 = (isK ? kbuf[0] : vbuf[0]) + lbase;
#pragma unroll
        for (int i = 0; i < 4; ++i)
            *(int4*)(d0 + i * 1024) = rg[i];
    }
    __syncthreads();  // buf[0] ready

    int pb = 0;
    for (int c = c0; c < c1b; ++c) {
        const bool more = (c + 1 < c1b);
        // ---- issue loads for chunk c+1 (in flight during compute) ----
        if (more) {
#pragma unroll
            for (int i = 0; i < 4; ++i)
                rg[i] = *(const int4*)(gp0 + (size_t)i * gstride);
            gp0 += adv;
        }
        // ---- compute chunk c from buf[pb] ----
        if (c < c1w) {
            const char* kbp = kbuf[pb];
            // S^T = K · Q^T, both q-tiles per kf read (2x reuse)
            floatx4 st[2][2];
#pragma unroll
            for (int u = 0; u < 2; ++u)
#pragma unroll
                for (int t = 0; t < 2; ++t) st[u][t] = (floatx4){0.f, 0.f, 0.f, 0.f};
            __builtin_amdgcn_s_setprio(1);   // T5: favor this wave while MFMAs issue
#pragma unroll
            for (int t = 0; t < 2; ++t)
#pragma unroll
                for (int s = 0; s < 8; ++s) {
                    short8 kf = *(const short8*)(kbp + ((t * 8 + s) * 64 + l) * 16);
                    st[0][t] = __builtin_amdgcn_mfma_f32_16x16x32_bf16(kf, qf[0][s], st[0][t], 0, 0, 0);
                    st[1][t] = __builtin_amdgcn_mfma_f32_16x16x32_bf16(kf, qf[1][s], st[1][t], 0, 0, 0);
                }
            __builtin_amdgcn_s_setprio(0);
            const int kl0 = c * 32;
            short8 pf[2];
#pragma unroll
            for (int u = 0; u < 2; ++u) {
                const int lim = 512 + qbw + u * 16 + m;
                const bool needmask = (kl0 + 31) > lim;
                float p[8];
#pragma unroll
                for (int t = 0; t < 2; ++t)
#pragma unroll
                    for (int r = 0; r < 4; ++r) {
                        float v = st[u][t][r] * sscale;
                        if (needmask) {
                            int key = kl0 + t * 16 + qd * 4 + r;
                            v = (key <= lim) ? v : -INFINITY;
                        }
                        p[t * 4 + r] = v;
                    }
                float mx = p[0];
#pragma unroll
                for (int i = 1; i < 8; ++i) mx = fmaxf(mx, p[i]);
                mx = fmaxf(mx, __shfl_xor(mx, 16, 64));
                mx = fmaxf(mx, __shfl_xor(mx, 32, 64));
                // T13 defer-max: if tile max grew <= 8 wave-wide, keep m_old.
                float mnew;
                if (__all(mx <= mi[u] + 8.0f)) mnew = mi[u];
                else                           mnew = fmaxf(mi[u], mx);
                const float alpha = exp2f(mi[u] - mnew);
                float ps = 0.f;
#pragma unroll
                for (int i = 0; i < 8; ++i) { p[i] = exp2f(p[i] - mnew); ps += p[i]; }
                ps += __shfl_xor(ps, 16, 64);
                ps += __shfl_xor(ps, 32, 64);
                li[u] = li[u] * alpha + ps;
                mi[u] = mnew;
                if (!__all(alpha == 1.0f)) {   // alpha==1 multiply is exact -> safe skip
#pragma unroll
                    for (int t = 0; t < 16; ++t) {
                        o[u][t][0] *= alpha; o[u][t][1] *= alpha;
                        o[u][t][2] *= alpha; o[u][t][3] *= alpha;
                    }
                }
                // pack P^T (bf16) + quad shuffle into B-fragment layout
                int pd0 = packbf(p[0], p[1]);
                int pd1 = packbf(p[2], p[3]);
                int pd2 = packbf(p[4], p[5]);
                int pd3 = packbf(p[6], p[7]);
                int x0 = __builtin_amdgcn_ds_bpermute(a0, pd0);
                int y0 = __builtin_amdgcn_ds_bpermute(a0, pd2);
                int x1 = __builtin_amdgcn_ds_bpermute(a0, pd1);
                int y1 = __builtin_amdgcn_ds_bpermute(a0, pd3);
                int x2 = __builtin_amdgcn_ds_bpermute(a1, pd0);
                int y2 = __builtin_amdgcn_ds_bpermute(a1, pd2);
                int x3 = __builtin_amdgcn_ds_bpermute(a1, pd1);
                int y3 = __builtin_amdgcn_ds_bpermute(a1, pd3);
                PFU pu;
                pu.i[0] = hi ? y0 : x0;
                pu.i[1] = hi ? y1 : x1;
                pu.i[2] = hi ? y2 : x2;
                pu.i[3] = hi ? y3 : x3;
                pf[u] = pu.v;
            }
            // O^T += V^T · P^T, both q-tiles per vf read (2x reuse)
            const char* vbp = vbuf[pb];
            __builtin_amdgcn_s_setprio(1);   // T5
#pragma unroll
            for (int t = 0; t < 16; ++t) {
                short8 vf = *(const short8*)(vbp + (t * 64 + l) * 16);
                o[0][t] = __builtin_amdgcn_mfma_f32_16x16x32_bf16(vf, pf[0], o[0][t], 0, 0, 0);
                o[1][t] = __builtin_amdgcn_mfma_f32_16x16x32_bf16(vf, pf[1], o[1][t], 0, 0, 0);
            }
            __builtin_amdgcn_s_setprio(0);
        }
        // ---- stage chunk c+1 (regs -> buf[pb^1]); rg dies here, same iter ----
        if (more) {
            char* dst = (isK ? kbuf[pb ^ 1] : vbuf[pb ^ 1]) + lbase;
#pragma unroll
            for (int i = 0; i < 4; ++i)
                *(int4*)(dst + i * 1024) = rg[i];
        }
        __syncthreads();
        pb ^= 1;
    }

    // ---- epilogue: O/l + residual, write out[b][d][n] (coalesced in n) ----
#pragma unroll
    for (int u = 0; u < 2; ++u) {
        const float inv = 1.f / li[u];
        const int ng = w * WIN + qbw + u * 16 + m;
        const float* xr  = x   + (size_t)b * DIM * NSEQ + ng;
        float*       orw = out + (size_t)b * DIM * NSEQ + ng;
#pragma unroll
        for (int t = 0; t < 16; ++t)
#pragma unroll
            for (int r = 0; r < 4; ++r) {
                int d = t * 16 + qd * 4 + r;
                orw[(size_t)d * NSEQ] = xr[(size_t)d * NSEQ] + o[u][t][r] * inv;
            }
    }
}

// ---------------------------------------------------------------------------
extern "C" void kernel_launch(void* const* d_in, const int* in_sizes, int n_in,
                              void* d_out, int out_size, void* d_ws, size_t ws_size,
                              hipStream_t stream) {
    const float* x  = (const float*)d_in[0];
    const float* Wq = (const float*)d_in[1];
    const float* bq = (const float*)d_in[2];
    const float* Wk = (const float*)d_in[3];
    const float* bk = (const float*)d_in[4];
    const float* Wv = (const float*)d_in[5];
    const float* bv = (const float*)d_in[6];

    char* ws = (char*)d_ws;
    const size_t SZ = (size_t)BATCH * NSEQ * DIM * sizeof(__hip_bfloat16);  // 32 MB
    __hip_bfloat16* qb_ = (__hip_bfloat16*)(ws);
    __hip_bfloat16* kb_ = (__hip_bfloat16*)(ws + SZ);
    __hip_bfloat16* vt_ = (__hip_bfloat16*)(ws + 2 * SZ);
    __hip_bfloat16* wb_ = (__hip_bfloat16*)(ws + 3 * SZ);                   // 384 KB

    k_wcast<<<dim3(192), 256, 0, stream>>>(Wq, Wk, Wv, wb_);
    k_prep<<<dim3(NSEQ / 64, BATCH), 256, 0, stream>>>(x, wb_, bq, bk, bv, qb_, kb_, vt_);
    k_attn<<<dim3(16, BATCH, 2), 512, 0, stream>>>(qb_, kb_, vt_, x, (float*)d_out);
}